// Round 1
// baseline (1352.346 us; speedup 1.0000x reference)
//
#include <hip/hip_runtime.h>
#include <hip/hip_bf16.h>

#define KK 9
#define C_IN 4
#define NF 16
#define TAPS (KK * C_IN)   // 36

__global__ __launch_bounds__(256) void onehot_conv_kernel(
    const float* __restrict__ times_in,
    const float* __restrict__ times_out,
    const int*   __restrict__ seg_ids,
    const int*   __restrict__ pred_ids,      // (n_out, K, C_IN)
    const float* __restrict__ decay_rate,    // (C_IN,)
    const float* __restrict__ kern,          // (K, C_IN, F)
    const float* __restrict__ bias,          // (F,)
    float*       __restrict__ out,           // (n_out, F)
    int n_in, int n_out)
{
    __shared__ float s_kern[TAPS * NF];   // 2304 B
    __shared__ float s_decay[C_IN];
    __shared__ float s_bias[NF];

    const int tid = threadIdx.x;
    for (int i = tid; i < TAPS * NF; i += blockDim.x) s_kern[i] = kern[i];
    if (tid < C_IN) {
        float x = decay_rate[tid];
        // numerically stable softplus: max(x,0) + log1p(exp(-|x|))
        s_decay[tid] = fmaxf(x, 0.0f) + log1pf(expf(-fabsf(x)));
    }
    if (tid < NF) s_bias[tid] = bias[tid];
    __syncthreads();

    const int o = blockIdx.x * blockDim.x + tid;
    if (o >= n_out) return;

    const float t_out = times_out[o];

    float acc[NF];
#pragma unroll
    for (int f = 0; f < NF; ++f) acc[f] = s_bias[f];

    const int4* pids = reinterpret_cast<const int4*>(pred_ids + (size_t)o * TAPS);

#pragma unroll
    for (int q = 0; q < TAPS / 4; ++q) {   // 9 x int4 loads (contiguous 144 B per thread)
        int4 v = pids[q];
        int ids[4] = { v.x, v.y, v.z, v.w };
#pragma unroll
        for (int j = 0; j < 4; ++j) {
            const int tap = q * 4 + j;          // tap = k*C_IN + c (C_IN == 4)
            const int id  = ids[j];
            const bool valid = (id < n_in);
            const int p = valid ? id : (n_in - 1);
            const float tp = times_in[p];
            const int   cp = seg_ids[p];
            const float dt = t_out - tp;
            const float w  = valid ? expf(-s_decay[cp] * dt) : 0.0f;
            const float* kr = &s_kern[tap * NF];
#pragma unroll
            for (int f = 0; f < NF; ++f) acc[f] = fmaf(w, kr[f], acc[f]);
        }
    }

    float4* op = reinterpret_cast<float4*>(out + (size_t)o * NF);
#pragma unroll
    for (int q = 0; q < 4; ++q)
        op[q] = make_float4(acc[q*4+0], acc[q*4+1], acc[q*4+2], acc[q*4+3]);
}

extern "C" void kernel_launch(void* const* d_in, const int* in_sizes, int n_in_arrs,
                              void* d_out, int out_size, void* d_ws, size_t ws_size,
                              hipStream_t stream) {
    const float* times_in   = (const float*)d_in[0];
    const float* times_out  = (const float*)d_in[1];
    const int*   seg_ids    = (const int*)d_in[2];
    const int*   pred_ids   = (const int*)d_in[3];
    const float* decay_rate = (const float*)d_in[4];
    const float* kern       = (const float*)d_in[5];
    const float* bias       = (const float*)d_in[6];

    const int n_in  = in_sizes[0];
    const int n_out = in_sizes[1];

    float* out = (float*)d_out;

    const int block = 256;
    const int grid  = (n_out + block - 1) / block;
    onehot_conv_kernel<<<grid, block, 0, stream>>>(
        times_in, times_out, seg_ids, pred_ids, decay_rate, kern, bias,
        out, n_in, n_out);
}